// Round 1
// baseline (562.101 us; speedup 1.0000x reference)
//
#include <hip/hip_runtime.h>
#include <cstddef>

#define NN 25600
#define BB 64
#define NPG 400
#define KK 16
#define EE (NN * KK)
#define DD 128
#define LL 4

// ---------------- weight prep: rearrange pre_W into [A|B] stacked (256x128),
// bias256, and post_W into combined (128x512) with mean folded into s ----------
__global__ __launch_bounds__(256) void prep_k(const float* __restrict__ preW,
                                              const float* __restrict__ preb,
                                              const float* __restrict__ postW,
                                              float* __restrict__ Wpre,
                                              float* __restrict__ bpre,
                                              float* __restrict__ Wpost) {
  int idx = blockIdx.x * 256 + threadIdx.x;
  const int n1 = LL * 256 * 128;          // 131072
  const int n2 = n1 + LL * 256;           // +1024
  const int n3 = n2 + LL * 128 * 512;     // +262144
  if (idx < n1) {
    int l = idx / 32768;
    int r = idx % 32768;
    int o = r / 128, k = r % 128;
    float v = (o < 128) ? preW[(size_t)l * 32768 + (size_t)o * 256 + k]
                        : preW[(size_t)l * 32768 + (size_t)(o - 128) * 256 + 128 + k];
    Wpre[idx] = v;
  } else if (idx < n2) {
    int r = idx - n1;
    int l = r / 256, o = r % 256;
    bpre[r] = (o < 128) ? 0.f : preb[l * 128 + (o - 128)];
  } else if (idx < n3) {
    int r = idx - n2;
    int l = r / 65536;
    int q = r % 65536;
    int o = q / 512, kk = q & 511;
    int j = kk >> 7, k = kk & 127;
    const float* base = postW + (size_t)l * 128 * 640 + (size_t)o * 640;
    float v;
    if (j == 0)      v = base[k];
    else if (j == 1) v = base[128 + k] * (1.f / 16.f) + base[256 + k];
    else if (j == 2) v = base[384 + k];
    else             v = base[512 + k];
    Wpost[r] = v;
  }
}

// ---------------- embed gather: h[n] = emb[node_feat[n]] ----------------
__global__ __launch_bounds__(256) void embed_k(const int* __restrict__ nf,
                                               const float* __restrict__ emb,
                                               float* __restrict__ h) {
  int idx = blockIdx.x * 256 + threadIdx.x;  // over N*32 float4s
  int n = idx >> 5;
  int d4 = idx & 31;
  int a = nf[n];
  float4 v = *(const float4*)(emb + (size_t)a * 128 + d4 * 4);
  *(float4*)(h + (size_t)n * 128 + d4 * 4) = v;
}

// ---------------- tiled fp32 GEMM: out[N x outc] = sum_j srcs[j] @ Wj^T (+bias)
// NSRC: number of 128-wide source arrays (K = NSRC*128)
// MODE 0: out = acc + bias
// MODE 1: out = s0 + relu((acc + bias) * snorm[row])   (in-place residual ok)
template <int NSRC, int MODE>
__global__ __launch_bounds__(256) void gemm_k(const float* __restrict__ s0,
                                              const float* __restrict__ s1,
                                              const float* __restrict__ s2,
                                              const float* __restrict__ s3,
                                              const float* __restrict__ W,
                                              const float* __restrict__ bias,
                                              float* __restrict__ out,
                                              const float* __restrict__ snorm,
                                              int outc) {
  __shared__ float hs[16][68];
  __shared__ float ws[16][132];
  const int tid = threadIdx.x;
  const int row0 = blockIdx.x * 64;
  const int cb = blockIdx.y * 128;
  const int tc = tid & 31, tr = tid >> 5;
  const int c0 = tc * 4, r0 = tr * 8;
  const int Ktot = NSRC * 128;
  float acc[8][4] = {};

  const int nchunk = NSRC * 8;
  for (int kc = 0; kc < nchunk; ++kc) {
    const int j = kc >> 3;
    const int k0 = (kc & 7) * 16;
    const float* sp = (NSRC == 1) ? s0 : ((j == 0) ? s0 : (j == 1) ? s1 : (j == 2) ? s2 : s3);
    // stage 64 rows x 16 k of source
    {
      const int lrow = tid >> 2;
      const int lk = (tid & 3) * 4;
      const float4 v = *(const float4*)(sp + (size_t)(row0 + lrow) * 128 + k0 + lk);
      hs[lk + 0][lrow] = v.x;
      hs[lk + 1][lrow] = v.y;
      hs[lk + 2][lrow] = v.z;
      hs[lk + 3][lrow] = v.w;
    }
    // stage 128 cols x 16 k of W
    {
      const int c = tid & 127;
      const int kg = tid >> 7;  // 0..1
#pragma unroll
      for (int rep = 0; rep < 2; ++rep) {
        const int lk = kg * 4 + rep * 8;
        const float4 v = *(const float4*)(W + (size_t)(cb + c) * Ktot + kc * 16 + lk);
        ws[lk + 0][c] = v.x;
        ws[lk + 1][c] = v.y;
        ws[lk + 2][c] = v.z;
        ws[lk + 3][c] = v.w;
      }
    }
    __syncthreads();
#pragma unroll
    for (int k = 0; k < 16; ++k) {
      const float4 wv = *(const float4*)&ws[k][c0];
      const float4 ha = *(const float4*)&hs[k][r0];
      const float4 hb = *(const float4*)&hs[k][r0 + 4];
      const float hv[8] = {ha.x, ha.y, ha.z, ha.w, hb.x, hb.y, hb.z, hb.w};
#pragma unroll
      for (int i = 0; i < 8; ++i) {
        acc[i][0] = fmaf(hv[i], wv.x, acc[i][0]);
        acc[i][1] = fmaf(hv[i], wv.y, acc[i][1]);
        acc[i][2] = fmaf(hv[i], wv.z, acc[i][2]);
        acc[i][3] = fmaf(hv[i], wv.w, acc[i][3]);
      }
    }
    __syncthreads();
  }
  // epilogue
#pragma unroll
  for (int i = 0; i < 8; ++i) {
    const int row = row0 + r0 + i;
    float4 v;
    float* vp = &v.x;
#pragma unroll
    for (int jj = 0; jj < 4; ++jj) {
      float a = acc[i][jj] + bias[cb + c0 + jj];
      if (MODE == 1) {
        a *= snorm[row];
        a = fmaxf(a, 0.f);
        a += s0[(size_t)row * 128 + c0 + jj];
      }
      vp[jj] = a;
    }
    *(float4*)(out + (size_t)row * outc + cb + c0) = v;
  }
}

// ---------------- edge aggregation: per-node (wave) gather of K=16 neighbors ----
__global__ __launch_bounds__(256) void edge_agg_k(const float* __restrict__ pre,  // N x 256 [A|B]
                                                  const float* __restrict__ h,
                                                  const int* __restrict__ src,
                                                  const float* __restrict__ eig,  // E x 2
                                                  float* __restrict__ s_out,
                                                  float* __restrict__ mx_out,
                                                  float* __restrict__ dir_out) {
  const int wave = threadIdx.x >> 6;
  const int lane = threadIdx.x & 63;
  const int n = blockIdx.x * 4 + wave;
  const int ebase = n * KK;
  float wv[KK];
  int sv[KK];
  float denom = 0.f;
#pragma unroll
  for (int e = 0; e < KK; ++e) {
    wv[e] = eig[(size_t)(ebase + e) * 2 + 1];
    sv[e] = src[ebase + e];
    denom += fabsf(wv[e]);
  }
  denom += 1e-8f;
  const float inv = 1.f / denom;
  float sum_ew = 0.f;
#pragma unroll
  for (int e = 0; e < KK; ++e) {
    wv[e] *= inv;
    sum_ew += wv[e];
  }
  float sA0 = 0.f, sA1 = 0.f, wA0 = 0.f, wA1 = 0.f;
  float mA0 = -3.402823466e+38f, mA1 = -3.402823466e+38f;
#pragma unroll
  for (int e = 0; e < KK; ++e) {
    const float* ap = pre + (size_t)sv[e] * 256;
    const float a0 = ap[lane];
    const float a1 = ap[64 + lane];
    sA0 += a0;
    sA1 += a1;
    wA0 = fmaf(wv[e], a0, wA0);
    wA1 = fmaf(wv[e], a1, wA1);
    mA0 = fmaxf(mA0, a0);
    mA1 = fmaxf(mA1, a1);
  }
  const float b0 = pre[(size_t)n * 256 + 128 + lane];
  const float b1 = pre[(size_t)n * 256 + 192 + lane];
  const float h0 = h[(size_t)n * 128 + lane];
  const float h1 = h[(size_t)n * 128 + 64 + lane];
  const size_t o0 = (size_t)n * 128 + lane;
  const size_t o1 = o0 + 64;
  s_out[o0] = sA0 + 16.f * b0;
  s_out[o1] = sA1 + 16.f * b1;
  mx_out[o0] = mA0 + b0;
  mx_out[o1] = mA1 + b1;
  dir_out[o0] = fabsf(wA0 + sum_ew * (b0 - h0));
  dir_out[o1] = fabsf(wA1 + sum_ew * (b1 - h1));
}

// ---------------- graph mean: hg[g] = mean over 400 rows ----------------
__global__ __launch_bounds__(128) void graph_reduce_k(const float* __restrict__ h,
                                                      float* __restrict__ hg) {
  const int g = blockIdx.x;
  const int d = threadIdx.x;
  const float* p = h + (size_t)g * NPG * 128 + d;
  float acc = 0.f;
  for (int i = 0; i < NPG; ++i) acc += p[(size_t)i * 128];
  hg[g * 128 + d] = acc * (1.f / (float)NPG);
}

// ---------------- readout MLP (tiny): 64x128 -> 64 -> 32 -> 128 ----------------
__global__ __launch_bounds__(256) void mlp_k(const float* __restrict__ hg,
                                             const float* __restrict__ W0, const float* __restrict__ b0,
                                             const float* __restrict__ W1, const float* __restrict__ b1,
                                             const float* __restrict__ W2, const float* __restrict__ b2,
                                             float* __restrict__ out) {
  __shared__ float y0[64 * 64];
  __shared__ float y1[64 * 32];
  const int tid = threadIdx.x;
  for (int idx = tid; idx < 64 * 64; idx += 256) {
    int g = idx >> 6, o = idx & 63;
    float a = b0[o];
    const float* hp = hg + g * 128;
    const float* wp = W0 + o * 128;
    for (int k = 0; k < 128; ++k) a = fmaf(hp[k], wp[k], a);
    y0[idx] = fmaxf(a, 0.f);
  }
  __syncthreads();
  for (int idx = tid; idx < 64 * 32; idx += 256) {
    int g = idx >> 5, o = idx & 31;
    float a = b1[o];
    const float* yp = y0 + g * 64;
    const float* wp = W1 + o * 64;
    for (int k = 0; k < 64; ++k) a = fmaf(yp[k], wp[k], a);
    y1[idx] = fmaxf(a, 0.f);
  }
  __syncthreads();
  for (int idx = tid; idx < 64 * 128; idx += 256) {
    int g = idx >> 7, o = idx & 127;
    float a = b2[o];
    const float* yp = y1 + g * 32;
    const float* wp = W2 + o * 32;
    for (int k = 0; k < 32; ++k) a = fmaf(yp[k], wp[k], a);
    out[idx] = a;
  }
}

extern "C" void kernel_launch(void* const* d_in, const int* in_sizes, int n_in,
                              void* d_out, int out_size, void* d_ws, size_t ws_size,
                              hipStream_t stream) {
  const int* node_feat = (const int*)d_in[0];
  const int* src = (const int*)d_in[1];
  // d_in[2] = dst (structure known: repeat(arange(N), 16)), unused
  const float* eig = (const float*)d_in[3];
  const float* snorm = (const float*)d_in[4];
  // d_in[5] = graph_ids (arange(N)//400), unused
  const float* emb = (const float*)d_in[6];
  const float* preW = (const float*)d_in[7];
  const float* preb = (const float*)d_in[8];
  const float* postW = (const float*)d_in[9];
  const float* postb = (const float*)d_in[10];
  const float* rW0 = (const float*)d_in[11];
  const float* rb0 = (const float*)d_in[12];
  const float* rW1 = (const float*)d_in[13];
  const float* rb1 = (const float*)d_in[14];
  const float* rW2 = (const float*)d_in[15];
  const float* rb2 = (const float*)d_in[16];
  float* out = (float*)d_out;

  float* ws = (float*)d_ws;
  float* h = ws;                               // N*128
  float* pre = h + (size_t)NN * 128;           // N*256
  float* sS = pre + (size_t)NN * 256;          // N*128
  float* sM = sS + (size_t)NN * 128;           // N*128
  float* sD = sM + (size_t)NN * 128;           // N*128
  float* Wpre = sD + (size_t)NN * 128;         // L*256*128
  float* bpre = Wpre + (size_t)LL * 256 * 128; // L*256
  float* Wpost = bpre + (size_t)LL * 256;      // L*128*512
  float* hg = Wpost + (size_t)LL * 128 * 512;  // 64*128

  // weight prep
  prep_k<<<1540, 256, 0, stream>>>(preW, preb, postW, Wpre, bpre, Wpost);
  // embedding gather
  embed_k<<<(NN * 32) / 256, 256, 0, stream>>>(node_feat, emb, h);

  for (int l = 0; l < LL; ++l) {
    gemm_k<1, 0><<<dim3(NN / 64, 2), 256, 0, stream>>>(
        h, h, h, h, Wpre + (size_t)l * 256 * 128, bpre + (size_t)l * 256, pre, nullptr, 256);
    edge_agg_k<<<NN / 4, 256, 0, stream>>>(pre, h, src, eig, sS, sM, sD);
    gemm_k<4, 1><<<dim3(NN / 64, 1), 256, 0, stream>>>(
        h, sS, sM, sD, Wpost + (size_t)l * 128 * 512, postb + (size_t)l * 128, h, snorm, 128);
  }

  graph_reduce_k<<<BB, 128, 0, stream>>>(h, hg);
  mlp_k<<<1, 256, 0, stream>>>(hg, rW0, rb0, rW1, rb1, rW2, rb2, out);
}

// Round 2
// 299.133 us; speedup vs baseline: 1.8791x; 1.8791x over previous
//
#include <hip/hip_runtime.h>
#include <cstddef>

#define NN 25600
#define BB 64
#define NPG 400
#define KK 16
#define LL 4

typedef _Float16 half_t;
typedef _Float16 h8 __attribute__((ext_vector_type(8)));
typedef _Float16 h4 __attribute__((ext_vector_type(4)));
typedef float f32x4 __attribute__((ext_vector_type(4)));

// ---------------- weight prep: split-fp16 weights -------------------------
// WpreH/L: [L][256][128]  rows 0..127 = Wp[:, :128] (A-side), 128..255 = Wp[:,128:] (B-side)
// WpostH/L: [L][128][512]  k-order [h | mean/16+s | mx | dir]
__global__ __launch_bounds__(256) void prep_k(const float* __restrict__ preW,
                                              const float* __restrict__ preb,
                                              const float* __restrict__ postW,
                                              half_t* __restrict__ WpreH,
                                              half_t* __restrict__ WpreL,
                                              float* __restrict__ bpre,
                                              half_t* __restrict__ WpostH,
                                              half_t* __restrict__ WpostL) {
  int idx = blockIdx.x * 256 + threadIdx.x;
  const int n1 = LL * 256 * 128;          // 131072
  const int n2 = n1 + LL * 256;           // +1024
  const int n3 = n2 + LL * 128 * 512;     // +262144
  if (idx < n1) {
    int l = idx / 32768;
    int r = idx % 32768;
    int o = r / 128, k = r % 128;
    float v = (o < 128) ? preW[(size_t)l * 32768 + (size_t)o * 256 + k]
                        : preW[(size_t)l * 32768 + (size_t)(o - 128) * 256 + 128 + k];
    half_t hi = (half_t)v;
    WpreH[idx] = hi;
    WpreL[idx] = (half_t)(v - (float)hi);
  } else if (idx < n2) {
    int r = idx - n1;
    int l = r / 256, o = r % 256;
    bpre[r] = (o < 128) ? 0.f : preb[l * 128 + (o - 128)];
  } else if (idx < n3) {
    int r = idx - n2;
    int l = r / 65536;
    int q = r % 65536;
    int o = q / 512, kk = q & 511;
    int j = kk >> 7, k = kk & 127;
    const float* base = postW + (size_t)l * 128 * 640 + (size_t)o * 640;
    float v;
    if (j == 0)      v = base[k];
    else if (j == 1) v = base[128 + k] * (1.f / 16.f) + base[256 + k];
    else if (j == 2) v = base[384 + k];
    else             v = base[512 + k];
    half_t hi = (half_t)v;
    WpostH[r] = hi;
    WpostL[r] = (half_t)(v - (float)hi);
  }
}

// ---------------- embed gather: h f32 + hcat[:,0:128) hi/lo ----------------
__global__ __launch_bounds__(256) void embed_k(const int* __restrict__ nf,
                                               const float* __restrict__ emb,
                                               float* __restrict__ hf,
                                               half_t* __restrict__ Hh,
                                               half_t* __restrict__ Hl) {
  int idx = blockIdx.x * 256 + threadIdx.x;  // over N*32 float4s
  int n = idx >> 5;
  int d4 = idx & 31;
  int a = nf[n];
  float4 v = *(const float4*)(emb + (size_t)a * 128 + d4 * 4);
  *(float4*)(hf + (size_t)n * 128 + d4 * 4) = v;
  h4 hi, lo;
  const float* vp = &v.x;
#pragma unroll
  for (int j = 0; j < 4; ++j) {
    half_t h = (half_t)vp[j];
    hi[j] = h;
    lo[j] = (half_t)(vp[j] - (float)h);
  }
  *(h4*)(Hh + (size_t)n * 512 + d4 * 4) = hi;
  *(h4*)(Hl + (size_t)n * 512 + d4 * 4) = lo;
}

// ---------------- split-fp16 MFMA GEMM -------------------------------------
// out[M x outc] = A @ W^T (+bias), A = Ah+Al (hcat, lda=512), W = Wh+Wl ([col][k], lda=Kt)
// block tile 64 rows x 128 cols, 4 waves (2m x 2n), wave tile 32x64
// MODE 0: outF[r*ldo+col] = acc + bias
// MODE 1: hn = outF + relu((acc+bias)*snorm[r]); outF=hn; Oh/Ol[r*512+col] = split(hn)
template <int MODE>
__global__ __launch_bounds__(256) void mfma_gemm_k(const half_t* __restrict__ Ah_g,
                                                   const half_t* __restrict__ Al_g,
                                                   const half_t* __restrict__ Wh_g,
                                                   const half_t* __restrict__ Wl_g,
                                                   int Kt,
                                                   const float* __restrict__ bias,
                                                   float* __restrict__ outF, int ldo,
                                                   half_t* __restrict__ Oh,
                                                   half_t* __restrict__ Ol,
                                                   const float* __restrict__ snorm) {
  __shared__ half_t Ahs[64][40];
  __shared__ half_t Als[64][40];
  __shared__ half_t Bhs[128][40];
  __shared__ half_t Bls[128][40];
  const int tid = threadIdx.x;
  const int r0 = blockIdx.x * 64;
  const int cb = blockIdx.y * 128;
  const int wid = tid >> 6, lane = tid & 63;
  const int wm = wid >> 1, wn = wid & 1;
  const int lr = lane & 15, lk = (lane >> 4) * 8;
  const int arow = tid >> 2, akp = (tid & 3) * 8;
  const int bcol = tid >> 1, bkp = (tid & 1) * 16;
  const int nk = Kt >> 5;
  f32x4 acc[2][4] = {};

  for (int kc = 0; kc < nk; ++kc) {
    const int k0 = kc * 32;
    // stage A (64 rows x 32 k, hi+lo)
    {
      const size_t g = (size_t)(r0 + arow) * 512 + k0 + akp;
      *(h8*)&Ahs[arow][akp] = *(const h8*)(Ah_g + g);
      *(h8*)&Als[arow][akp] = *(const h8*)(Al_g + g);
    }
    // stage B (128 cols x 32 k, hi+lo)
    {
      const size_t g = (size_t)(cb + bcol) * Kt + k0 + bkp;
      *(h8*)&Bhs[bcol][bkp] = *(const h8*)(Wh_g + g);
      *(h8*)&Bhs[bcol][bkp + 8] = *(const h8*)(Wh_g + g + 8);
      *(h8*)&Bls[bcol][bkp] = *(const h8*)(Wl_g + g);
      *(h8*)&Bls[bcol][bkp + 8] = *(const h8*)(Wl_g + g + 8);
    }
    __syncthreads();
    h8 af[2][2], bf[4][2];
#pragma unroll
    for (int mi = 0; mi < 2; ++mi) {
      const int r = wm * 32 + mi * 16 + lr;
      af[mi][0] = *(const h8*)&Ahs[r][lk];
      af[mi][1] = *(const h8*)&Als[r][lk];
    }
#pragma unroll
    for (int nj = 0; nj < 4; ++nj) {
      const int c = wn * 64 + nj * 16 + lr;
      bf[nj][0] = *(const h8*)&Bhs[c][lk];
      bf[nj][1] = *(const h8*)&Bls[c][lk];
    }
#pragma unroll
    for (int mi = 0; mi < 2; ++mi)
#pragma unroll
      for (int nj = 0; nj < 4; ++nj) {
        acc[mi][nj] = __builtin_amdgcn_mfma_f32_16x16x32_f16(af[mi][0], bf[nj][0], acc[mi][nj], 0, 0, 0);
        acc[mi][nj] = __builtin_amdgcn_mfma_f32_16x16x32_f16(af[mi][0], bf[nj][1], acc[mi][nj], 0, 0, 0);
        acc[mi][nj] = __builtin_amdgcn_mfma_f32_16x16x32_f16(af[mi][1], bf[nj][0], acc[mi][nj], 0, 0, 0);
      }
    __syncthreads();
  }
  // epilogue: C/D layout col=lane&15, row=(lane>>4)*4+q
#pragma unroll
  for (int mi = 0; mi < 2; ++mi) {
    const int rowb = r0 + wm * 32 + mi * 16 + (lane >> 4) * 4;
#pragma unroll
    for (int nj = 0; nj < 4; ++nj) {
      const int col = cb + wn * 64 + nj * 16 + lr;
      const float bv = bias[col];
#pragma unroll
      for (int q = 0; q < 4; ++q) {
        const int r = rowb + q;
        float a = acc[mi][nj][q] + bv;
        if (MODE == 0) {
          outF[(size_t)r * ldo + col] = a;
        } else {
          a *= snorm[r];
          a = fmaxf(a, 0.f);
          const float hn = outF[(size_t)r * ldo + col] + a;
          outF[(size_t)r * ldo + col] = hn;
          const half_t hi = (half_t)hn;
          Oh[(size_t)r * 512 + col] = hi;
          Ol[(size_t)r * 512 + col] = (half_t)(hn - (float)hi);
        }
      }
    }
  }
}

// ---------------- edge aggregation → hcat slices (hi/lo) -------------------
__global__ __launch_bounds__(256) void edge_agg_k(const float* __restrict__ pre,  // N x 256 [A|B]
                                                  const float* __restrict__ h,
                                                  const int* __restrict__ src,
                                                  const float* __restrict__ eig,  // E x 2
                                                  half_t* __restrict__ Oh,
                                                  half_t* __restrict__ Ol) {
  const int wave = threadIdx.x >> 6;
  const int lane = threadIdx.x & 63;
  const int n = blockIdx.x * 4 + wave;
  const int ebase = n * KK;
  float wv[KK];
  int sv[KK];
  float denom = 0.f;
#pragma unroll
  for (int e = 0; e < KK; ++e) {
    wv[e] = eig[(size_t)(ebase + e) * 2 + 1];
    sv[e] = src[ebase + e];
    denom += fabsf(wv[e]);
  }
  denom += 1e-8f;
  const float inv = 1.f / denom;
  float sum_ew = 0.f;
#pragma unroll
  for (int e = 0; e < KK; ++e) {
    wv[e] *= inv;
    sum_ew += wv[e];
  }
  float sA0 = 0.f, sA1 = 0.f, wA0 = 0.f, wA1 = 0.f;
  float mA0 = -3.402823466e+38f, mA1 = -3.402823466e+38f;
#pragma unroll
  for (int e = 0; e < KK; ++e) {
    const float* ap = pre + (size_t)sv[e] * 256;
    const float a0 = ap[lane];
    const float a1 = ap[64 + lane];
    sA0 += a0;
    sA1 += a1;
    wA0 = fmaf(wv[e], a0, wA0);
    wA1 = fmaf(wv[e], a1, wA1);
    mA0 = fmaxf(mA0, a0);
    mA1 = fmaxf(mA1, a1);
  }
  const float b0 = pre[(size_t)n * 256 + 128 + lane];
  const float b1 = pre[(size_t)n * 256 + 192 + lane];
  const float h0 = h[(size_t)n * 128 + lane];
  const float h1 = h[(size_t)n * 128 + 64 + lane];
  const size_t base = (size_t)n * 512;
  auto wr = [&](size_t off, float v) {
    const half_t hi = (half_t)v;
    Oh[off] = hi;
    Ol[off] = (half_t)(v - (float)hi);
  };
  wr(base + 128 + lane, sA0 + 16.f * b0);
  wr(base + 192 + lane, sA1 + 16.f * b1);
  wr(base + 256 + lane, mA0 + b0);
  wr(base + 320 + lane, mA1 + b1);
  wr(base + 384 + lane, fabsf(wA0 + sum_ew * (b0 - h0)));
  wr(base + 448 + lane, fabsf(wA1 + sum_ew * (b1 - h1)));
}

// ---------------- fused graph-mean + readout MLP (64 blocks) ---------------
__global__ __launch_bounds__(256) void reduce_mlp_k(const float* __restrict__ h,
                                                    const float* __restrict__ W0, const float* __restrict__ b0,
                                                    const float* __restrict__ W1, const float* __restrict__ b1,
                                                    const float* __restrict__ W2, const float* __restrict__ b2,
                                                    float* __restrict__ out) {
  __shared__ float hgs[128];
  __shared__ float red[128];
  __shared__ float y0s[64];
  __shared__ float y1s[32];
  __shared__ float wb[64 * 130];
  const int g = blockIdx.x;
  const int t = threadIdx.x;
  // graph mean: 256 threads, 2 half-ranges of 200 rows
  {
    const int d = t & 127, hf = t >> 7;
    const float* p = h + ((size_t)g * NPG + (size_t)hf * 200) * 128 + d;
    float acc = 0.f;
    for (int i = 0; i < 200; ++i) acc += p[(size_t)i * 128];
    if (hf) red[d] = acc;
    __syncthreads();
    if (!hf) hgs[d] = (acc + red[d]) * (1.f / (float)NPG);
  }
  __syncthreads();
  // layer 0: 128 -> 64, relu
  for (int idx = t; idx < 64 * 128; idx += 256) {
    wb[(idx >> 7) * 130 + (idx & 127)] = W0[idx];
  }
  __syncthreads();
  if (t < 64) {
    float a = b0[t];
    const float* w = &wb[t * 130];
    for (int k = 0; k < 128; ++k) a = fmaf(hgs[k], w[k], a);
    y0s[t] = fmaxf(a, 0.f);
  }
  __syncthreads();
  // layer 1: 64 -> 32, relu
  for (int idx = t; idx < 32 * 64; idx += 256) {
    wb[(idx >> 6) * 66 + (idx & 63)] = W1[idx];
  }
  __syncthreads();
  if (t < 32) {
    float a = b1[t];
    const float* w = &wb[t * 66];
    for (int k = 0; k < 64; ++k) a = fmaf(y0s[k], w[k], a);
    y1s[t] = fmaxf(a, 0.f);
  }
  __syncthreads();
  // layer 2: 32 -> 128
  for (int idx = t; idx < 128 * 32; idx += 256) {
    wb[(idx >> 5) * 34 + (idx & 31)] = W2[idx];
  }
  __syncthreads();
  if (t < 128) {
    float a = b2[t];
    const float* w = &wb[t * 34];
    for (int k = 0; k < 32; ++k) a = fmaf(y1s[k], w[k], a);
    out[(size_t)g * 128 + t] = a;
  }
}

extern "C" void kernel_launch(void* const* d_in, const int* in_sizes, int n_in,
                              void* d_out, int out_size, void* d_ws, size_t ws_size,
                              hipStream_t stream) {
  const int* node_feat = (const int*)d_in[0];
  const int* src = (const int*)d_in[1];
  // d_in[2] = dst (repeat(arange(N),16)), unused
  const float* eig = (const float*)d_in[3];
  const float* snorm = (const float*)d_in[4];
  // d_in[5] = graph_ids, unused
  const float* emb = (const float*)d_in[6];
  const float* preW = (const float*)d_in[7];
  const float* preb = (const float*)d_in[8];
  const float* postW = (const float*)d_in[9];
  const float* postb = (const float*)d_in[10];
  const float* rW0 = (const float*)d_in[11];
  const float* rb0 = (const float*)d_in[12];
  const float* rW1 = (const float*)d_in[13];
  const float* rb1 = (const float*)d_in[14];
  const float* rW2 = (const float*)d_in[15];
  const float* rb2 = (const float*)d_in[16];
  float* out = (float*)d_out;

  // workspace layout
  half_t* Hh = (half_t*)d_ws;                       // N*512 halves
  half_t* Hl = Hh + (size_t)NN * 512;               // N*512
  float* Hf = (float*)(Hl + (size_t)NN * 512);      // N*128 f32
  float* pre = Hf + (size_t)NN * 128;               // N*256 f32
  half_t* WpreH = (half_t*)(pre + (size_t)NN * 256);  // L*256*128
  half_t* WpreL = WpreH + (size_t)LL * 256 * 128;
  half_t* WpostH = WpreL + (size_t)LL * 256 * 128;    // L*128*512
  half_t* WpostL = WpostH + (size_t)LL * 128 * 512;
  float* bpre = (float*)(WpostL + (size_t)LL * 128 * 512);  // L*256

  prep_k<<<1540, 256, 0, stream>>>(preW, preb, postW, WpreH, WpreL, bpre, WpostH, WpostL);
  embed_k<<<(NN * 32) / 256, 256, 0, stream>>>(node_feat, emb, Hf, Hh, Hl);

  for (int l = 0; l < LL; ++l) {
    mfma_gemm_k<0><<<dim3(NN / 64, 2), 256, 0, stream>>>(
        Hh, Hl, WpreH + (size_t)l * 32768, WpreL + (size_t)l * 32768, 128,
        bpre + (size_t)l * 256, pre, 256, nullptr, nullptr, nullptr);
    edge_agg_k<<<NN / 4, 256, 0, stream>>>(pre, Hf, src, eig, Hh, Hl);
    mfma_gemm_k<1><<<dim3(NN / 64, 1), 256, 0, stream>>>(
        Hh, Hl, WpostH + (size_t)l * 65536, WpostL + (size_t)l * 65536, 512,
        postb + (size_t)l * 128, Hf, 128, Hh, Hl, snorm);
  }

  reduce_mlp_k<<<BB, 256, 0, stream>>>(Hf, rW0, rb0, rW1, rb1, rW2, rb2, out);
}